// Round 5
// baseline (258.223 us; speedup 1.0000x reference)
//
#include <hip/hip_runtime.h>
#include <cstdint>
#include <cstddef>

#define EMBED 1024
#define HEAD  128
#define BATCH 4
#define SEQ   4096
#define KSC   0.04508422f   // log2(e)/sqrt(1024)

typedef __attribute__((ext_vector_type(4))) float f32x4;
typedef __attribute__((ext_vector_type(16))) float f32x16;
typedef __attribute__((ext_vector_type(8))) short s16x8;
typedef __attribute__((ext_vector_type(4))) int i32x4;
typedef __attribute__((ext_vector_type(4))) unsigned short u16x4;

__device__ __forceinline__ unsigned short f2bf(float f) {
    union { float f; unsigned u; } v; v.f = f;
    unsigned r = v.u + 0x7fffu + ((v.u >> 16) & 1u);
    return (unsigned short)(r >> 16);
}

__device__ __forceinline__ int cvtpk(float lo, float hi_) {
    int r;
    asm("v_cvt_pk_bf16_f32 %0, %1, %2" : "=v"(r) : "v"(lo), "v"(hi_));
    return r;
}

// ---- W [1024][128] f32 x3 -> Wt [384][1024] bf16 (rows: 0-127 Q, 128-255 K, 256-383 V)
__global__ __launch_bounds__(256) void wt_kernel(const float* __restrict__ Wq,
                                                 const float* __restrict__ Wk,
                                                 const float* __restrict__ Wv,
                                                 unsigned short* __restrict__ Wt) {
    int idx = blockIdx.x * 256 + threadIdx.x;
    int sel = idx >> 17;
    int r   = idx & 131071;
    const float* W = (sel == 0) ? Wq : (sel == 1) ? Wk : Wv;
    int h = r >> 10, k = r & 1023;
    Wt[(size_t)(sel * 128 + h) * EMBED + k] = f2bf(W[(size_t)k * HEAD + h]);
}

// ---- projection GEMM, m93 structure: grid (128, 3), tile 128x128, BK=64,
// 4 waves (2x2), each wave 64x64 = 4x4 16x16 frags
__global__ __launch_bounds__(256) void proj_kernel(const float* __restrict__ ctx,
                                                   const unsigned short* __restrict__ Wt,
                                                   unsigned short* __restrict__ QKV) {
    __shared__ __align__(16) short As[128 * 72];
    __shared__ __align__(16) short Bs[128 * 72];
    const int tid = threadIdx.x;
    const int lane = tid & 63, w = tid >> 6;
    const int wr = w >> 1, wc = w & 1;
    const int lr = lane & 15, lk = lane >> 4;
    const int m0 = blockIdx.x * 128;
    const unsigned short* Wts = Wt + (size_t)blockIdx.y * 131072;
    unsigned short* outp = QKV + (size_t)blockIdx.y * 2097152;

    f32x4 zero = {0.f, 0.f, 0.f, 0.f};
    f32x4 acc[4][4];
    #pragma unroll
    for (int i = 0; i < 4; ++i)
        #pragma unroll
        for (int jn = 0; jn < 4; ++jn) acc[i][jn] = zero;

    for (int kk = 0; kk < EMBED; kk += 64) {
        __syncthreads();
        #pragma unroll
        for (int t = 0; t < 4; ++t) {
            int c = tid + t * 256;             // 1024 chunks of 8 elems
            int row = c >> 3, cg = c & 7;
            const float* src = ctx + (size_t)(m0 + row) * EMBED + kk + cg * 8;
            f32x4 x0 = *(const f32x4*)src;
            f32x4 x1 = *(const f32x4*)(src + 4);
            s16x8 cv;
            cv[0] = (short)f2bf(x0[0]); cv[1] = (short)f2bf(x0[1]);
            cv[2] = (short)f2bf(x0[2]); cv[3] = (short)f2bf(x0[3]);
            cv[4] = (short)f2bf(x1[0]); cv[5] = (short)f2bf(x1[1]);
            cv[6] = (short)f2bf(x1[2]); cv[7] = (short)f2bf(x1[3]);
            *(s16x8*)&As[row * 72 + cg * 8] = cv;
            *(s16x8*)&Bs[row * 72 + cg * 8] =
                *(const s16x8*)(Wts + (size_t)row * EMBED + kk + cg * 8);
        }
        __syncthreads();
        s16x8 af[4][2], bfr[4][2];
        #pragma unroll
        for (int mi = 0; mi < 4; ++mi)
            #pragma unroll
            for (int k2 = 0; k2 < 2; ++k2)
                af[mi][k2] = *(const s16x8*)&As[(wr * 64 + mi * 16 + lr) * 72 + k2 * 32 + lk * 8];
        #pragma unroll
        for (int ni = 0; ni < 4; ++ni)
            #pragma unroll
            for (int k2 = 0; k2 < 2; ++k2)
                bfr[ni][k2] = *(const s16x8*)&Bs[(wc * 64 + ni * 16 + lr) * 72 + k2 * 32 + lk * 8];
        #pragma unroll
        for (int k2 = 0; k2 < 2; ++k2)
            #pragma unroll
            for (int mi = 0; mi < 4; ++mi)
                #pragma unroll
                for (int ni = 0; ni < 4; ++ni)
                    acc[mi][ni] = __builtin_amdgcn_mfma_f32_16x16x32_bf16(af[mi][k2], bfr[ni][k2], acc[mi][ni], 0, 0, 0);
    }
    #pragma unroll
    for (int mi = 0; mi < 4; ++mi) {
        int row = m0 + wr * 64 + mi * 16 + lk * 4;
        #pragma unroll
        for (int ni = 0; ni < 4; ++ni) {
            int col = wc * 64 + ni * 16 + lr;
            #pragma unroll
            for (int r = 0; r < 4; ++r)
                outp[(size_t)(row + r) * HEAD + col] = f2bf(acc[mi][ni][r]);
        }
    }
}

// ---- V [B*T][128] bf16 -> Vt [B][128][T] bf16
__global__ __launch_bounds__(256) void vt_kernel(const unsigned short* __restrict__ V,
                                                 unsigned short* __restrict__ Vt) {
    __shared__ __align__(16) unsigned short L[64][136];
    const int tid = threadIdx.x;
    const int t0 = blockIdx.x * 64;
    const int b  = t0 >> 12;
    const int tl = t0 & (SEQ - 1);
    #pragma unroll
    for (int j = 0; j < 4; ++j) {
        int c = tid + j * 256;
        int row = c >> 4, cg = c & 15;
        *(s16x8*)&L[row][cg * 8] =
            *(const s16x8*)(V + (size_t)(t0 + row) * HEAD + cg * 8);
    }
    __syncthreads();
    #pragma unroll
    for (int j = 0; j < 4; ++j) {
        int c = tid + j * 256;
        int h = c >> 3, tg = c & 7;
        s16x8 y;
        #pragma unroll
        for (int e = 0; e < 8; ++e) y[e] = (short)L[tg * 8 + e][h];
        *(s16x8*)(Vt + ((size_t)b * HEAD + h) * SEQ + tl + tg * 8) = y;
    }
}

// ---- flash attention: 4 waves x 32 q-rows, 32x32x16 MFMA, swapped QK^T,
// in-register softmax, KV chunks of 256 keys, single-buffered LDS (32KB, 4 blocks/CU),
// T14 reg-staged early-issue loads
__global__ __launch_bounds__(256, 4) void attn_kernel(const unsigned short* __restrict__ Q,
                                                      const unsigned short* __restrict__ K,
                                                      const unsigned short* __restrict__ Vt,
                                                      unsigned short* __restrict__ po,
                                                      float* __restrict__ pml) {
    __shared__ __align__(16) char smem[32768];   // K 16KB + Vt 16KB, XOR-swizzled
    const int tid = threadIdx.x;
    const int lane = tid & 63, w = tid >> 6;
    const int l31 = lane & 31, hi = lane >> 5;
    const int hi16 = hi << 4;

    const int b = blockIdx.x / 272;
    int t = blockIdx.x % 272;
    int qt = 0, cum = 0;
    while (cum + ((qt >> 1) + 1) <= t) { cum += (qt >> 1) + 1; ++qt; }
    const int c = t - cum;
    const int nj = min(4, 2 * qt + 2 - 4 * c);
    const int kb0 = c * 256;
    const int slot = b * 272 + cum + c;

    // Q fragments in registers: Q[q=l31 (+w*32)][d = dt*16 + hi*8 + e]
    const unsigned short* qp = Q + ((size_t)(b * SEQ + qt * 128 + w * 32 + l31)) * HEAD + hi * 8;
    s16x8 qf[8];
    #pragma unroll
    for (int dt = 0; dt < 8; ++dt) qf[dt] = *(const s16x8*)(qp + dt * 16);

    f32x16 o0, o1, o2, o3;
    #pragma unroll
    for (int r = 0; r < 16; ++r) { o0[r] = 0.f; o1[r] = 0.f; o2[r] = 0.f; o3[r] = 0.f; }
    float m_run = -1e30f, l_run = 0.f;

    const int krow = tid >> 4, kch = tid & 15;   // K stage: 16 rows x 16 chunks per pass
    const int vdr  = tid >> 3, vch = tid & 7;    // V stage: 32 rows x 8 chunks per pass

    s16x8 kst[4], vst[4];
    #pragma unroll
    for (int p = 0; p < 4; ++p) {
        kst[p] = *(const s16x8*)(K + ((size_t)(b * SEQ + kb0 + krow + p * 16)) * HEAD + kch * 8);
        vst[p] = *(const s16x8*)(Vt + ((size_t)(b * HEAD + vdr + p * 32)) * SEQ + kb0 + vch * 8);
    }
    #pragma unroll
    for (int p = 0; p < 4; ++p) {
        int r0 = krow + p * 16;
        *(s16x8*)(smem + r0 * 256 + ((kch * 16) ^ ((r0 & 7) << 4))) = kst[p];
        int d0 = vdr + p * 32;
        *(s16x8*)(smem + 16384 + d0 * 128 + ((vch * 16) ^ ((d0 & 7) << 4))) = vst[p];
    }
    __syncthreads();

    for (int j = 0; j < nj; ++j) {
        const int kb = kb0 + j * 64;
        if (j + 1 < nj) {                        // early-issue next-tile loads (T14)
            int kbn = kb + 64;
            #pragma unroll
            for (int p = 0; p < 4; ++p) {
                kst[p] = *(const s16x8*)(K + ((size_t)(b * SEQ + kbn + krow + p * 16)) * HEAD + kch * 8);
                vst[p] = *(const s16x8*)(Vt + ((size_t)(b * HEAD + vdr + p * 32)) * SEQ + kbn + vch * 8);
            }
        }

        // ---- QK^T swapped: st[t][r] = S[k = 32t + crow(r,hi)][q = l31]
        f32x16 st0, st1;
        #pragma unroll
        for (int r = 0; r < 16; ++r) { st0[r] = 0.f; st1[r] = 0.f; }
        const int sw = (l31 & 7) << 4;
        const char* kbase0 = smem + l31 * 256;
        const char* kbase1 = kbase0 + 32 * 256;
        __builtin_amdgcn_s_setprio(1);
        #pragma unroll
        for (int dt = 0; dt < 8; ++dt) {
            s16x8 ka0 = *(const s16x8*)(kbase0 + ((dt * 32 + hi16) ^ sw));
            s16x8 ka1 = *(const s16x8*)(kbase1 + ((dt * 32 + hi16) ^ sw));
            st0 = __builtin_amdgcn_mfma_f32_32x32x16_bf16(ka0, qf[dt], st0, 0, 0, 0);
            st1 = __builtin_amdgcn_mfma_f32_32x32x16_bf16(ka1, qf[dt], st1, 0, 0, 0);
        }
        __builtin_amdgcn_s_setprio(0);

        // ---- causal mask (diagonal tiles only)
        if (4 * c + j >= 2 * qt) {
            const int qg = qt * 128 + w * 32 + l31;
            #pragma unroll
            for (int r = 0; r < 16; ++r) {
                int crow = (r & 3) + 8 * (r >> 2) + 4 * hi;
                if (kb + crow > qg)      st0[r] = -3e37f;
                if (kb + 32 + crow > qg) st1[r] = -3e37f;
            }
        }

        // ---- online softmax, fully in-register (one cross-half shuffle)
        float mx = st0[0];
        #pragma unroll
        for (int r = 1; r < 16; ++r) mx = fmaxf(mx, st0[r]);
        #pragma unroll
        for (int r = 0; r < 16; ++r) mx = fmaxf(mx, st1[r]);
        mx = fmaxf(mx, __shfl_xor(mx, 32));
        float mt = mx * KSC;
        if (!__all(mt <= m_run + 8.0f)) {        // defer-max (T13)
            float mn = fmaxf(m_run, mt);
            float f = exp2f(m_run - mn);
            l_run *= f;
            int fi = __float_as_int(f);
            #pragma unroll
            for (int r = 0; r < 16; ++r) {       // transpose f to reg-domain q
                int srcb = 4 * ((r & 3) + 8 * (r >> 2)) + 16 * hi;
                float fr = __int_as_float(__builtin_amdgcn_ds_bpermute(srcb, fi));
                o0[r] *= fr; o1[r] *= fr; o2[r] *= fr; o3[r] *= fr;
            }
            m_run = mn;
        }
        float rs = 0.f;
        #pragma unroll
        for (int r = 0; r < 16; ++r) {
            st0[r] = exp2f(fmaf(st0[r], KSC, -m_run)); rs += st0[r];
            st1[r] = exp2f(fmaf(st1[r], KSC, -m_run)); rs += st1[r];
        }
        rs += __shfl_xor(rs, 32);
        l_run += rs;

        // ---- P -> bf16 PV A-frags in-register (T12: cvt_pk + permlane32_swap)
        int a0 = cvtpk(st0[0], st0[1]),   b0 = cvtpk(st0[4], st0[5]);
        int a1 = cvtpk(st0[2], st0[3]),   b1 = cvtpk(st0[6], st0[7]);
        int a2 = cvtpk(st0[8], st0[9]),   b2 = cvtpk(st0[12], st0[13]);
        int a3 = cvtpk(st0[10], st0[11]), b3 = cvtpk(st0[14], st0[15]);
        int a4 = cvtpk(st1[0], st1[1]),   b4 = cvtpk(st1[4], st1[5]);
        int a5 = cvtpk(st1[2], st1[3]),   b5 = cvtpk(st1[6], st1[7]);
        int a6 = cvtpk(st1[8], st1[9]),   b6 = cvtpk(st1[12], st1[13]);
        int a7 = cvtpk(st1[10], st1[11]), b7 = cvtpk(st1[14], st1[15]);
        asm volatile("v_permlane32_swap_b32 %0, %1" : "+v"(a0), "+v"(b0));
        asm volatile("v_permlane32_swap_b32 %0, %1" : "+v"(a1), "+v"(b1));
        asm volatile("v_permlane32_swap_b32 %0, %1" : "+v"(a2), "+v"(b2));
        asm volatile("v_permlane32_swap_b32 %0, %1" : "+v"(a3), "+v"(b3));
        asm volatile("v_permlane32_swap_b32 %0, %1" : "+v"(a4), "+v"(b4));
        asm volatile("v_permlane32_swap_b32 %0, %1" : "+v"(a5), "+v"(b5));
        asm volatile("v_permlane32_swap_b32 %0, %1" : "+v"(a6), "+v"(b6));
        asm volatile("v_permlane32_swap_b32 %0, %1" : "+v"(a7), "+v"(b7));
        i32x4 pw0 = {a0, a1, b0, b1}; s16x8 pa0 = *(s16x8*)&pw0;
        i32x4 pw1 = {a2, a3, b2, b3}; s16x8 pa1 = *(s16x8*)&pw1;
        i32x4 pw2 = {a4, a5, b4, b5}; s16x8 pa2 = *(s16x8*)&pw2;
        i32x4 pw3 = {a6, a7, b6, b7}; s16x8 pa3 = *(s16x8*)&pw3;

        // ---- PV: o[nt] += P(32x64) * V(64 x 32d-tile)
        __builtin_amdgcn_s_setprio(1);
        #define PV_NT(oo, nt) { \
            const int vr = (nt) * 32 + l31; \
            const int vsw = (vr & 7) << 4; \
            const char* vb = smem + 16384 + vr * 128; \
            oo = __builtin_amdgcn_mfma_f32_32x32x16_bf16(pa0, *(const s16x8*)(vb + ((0  + hi16) ^ vsw)), oo, 0, 0, 0); \
            oo = __builtin_amdgcn_mfma_f32_32x32x16_bf16(pa1, *(const s16x8*)(vb + ((32 + hi16) ^ vsw)), oo, 0, 0, 0); \
            oo = __builtin_amdgcn_mfma_f32_32x32x16_bf16(pa2, *(const s16x8*)(vb + ((64 + hi16) ^ vsw)), oo, 0, 0, 0); \
            oo = __builtin_amdgcn_mfma_f32_32x32x16_bf16(pa3, *(const s16x8*)(vb + ((96 + hi16) ^ vsw)), oo, 0, 0, 0); }
        PV_NT(o0, 0) PV_NT(o1, 1) PV_NT(o2, 2) PV_NT(o3, 3)
        #undef PV_NT
        __builtin_amdgcn_s_setprio(0);

        if (j + 1 < nj) {                        // single buffer: wait for readers, then overwrite
            __syncthreads();
            #pragma unroll
            for (int p = 0; p < 4; ++p) {
                int r0 = krow + p * 16;
                *(s16x8*)(smem + r0 * 256 + ((kch * 16) ^ ((r0 & 7) << 4))) = kst[p];
                int d0 = vdr + p * 32;
                *(s16x8*)(smem + 16384 + d0 * 128 + ((vch * 16) ^ ((d0 & 7) << 4))) = vst[p];
            }
            __syncthreads();
        }
    }

    // ---- write partials: O is q=crow(reg), d=lane
    unsigned short* pob = po + (size_t)slot * 16384;
    #define STORE_NT(oo, nt) { \
        _Pragma("unroll") \
        for (int r = 0; r < 16; ++r) { \
            int qin = w * 32 + (r & 3) + 8 * (r >> 2) + 4 * hi; \
            pob[qin * 128 + (nt) * 32 + l31] = f2bf(oo[r]); \
        } }
    STORE_NT(o0, 0) STORE_NT(o1, 1) STORE_NT(o2, 2) STORE_NT(o3, 3)
    #undef STORE_NT
    if (lane < 32) {
        float* pm = pml + (size_t)slot * 256 + (w * 32 + lane) * 2;
        pm[0] = m_run; pm[1] = l_run;
    }
}

// ---- combine partials: out[q][:] = sum_c w_c*O_c / sum_c w_c*l_c
__global__ __launch_bounds__(256) void combine_kernel(const unsigned short* __restrict__ po,
                                                      const float* __restrict__ pml,
                                                      float* __restrict__ out) {
    const int tid = threadIdx.x;
    const int row = blockIdx.x * 8 + (tid >> 5);
    const int l32 = tid & 31;
    const int b = row >> 12, q = row & 4095;
    const int qt = q >> 7, qr = q & 127;
    const int nc = (q >> 8) + 1;
    const int cum = ((qt >> 1) + (qt & 1)) * ((qt >> 1) + 1);
    const size_t bslot = (size_t)b * 272 + cum;

    float M = -1e30f;
    for (int cc = 0; cc < nc; ++cc)
        M = fmaxf(M, pml[(bslot + cc) * 256 + qr * 2]);
    float L = 0.f;
    f32x4 acc = {0.f, 0.f, 0.f, 0.f};
    for (int cc = 0; cc < nc; ++cc) {
        const float* pm = pml + (bslot + cc) * 256 + qr * 2;
        float wgt = exp2f(pm[0] - M);
        L += wgt * pm[1];
        u16x4 x = *(const u16x4*)(po + (bslot + cc) * 16384 + qr * 128 + l32 * 4);
        #pragma unroll
        for (int e = 0; e < 4; ++e) {
            union { unsigned u; float f; } cv; cv.u = ((unsigned)x[e]) << 16;
            acc[e] += wgt * cv.f;
        }
    }
    float inv = 1.f / L;
    f32x4 y = {acc[0] * inv, acc[1] * inv, acc[2] * inv, acc[3] * inv};
    *(f32x4*)(out + (size_t)row * HEAD + l32 * 4) = y;
}

extern "C" void kernel_launch(void* const* d_in, const int* in_sizes, int n_in,
                              void* d_out, int out_size, void* d_ws, size_t ws_size,
                              hipStream_t stream) {
    const float* ctx = (const float*)d_in[0];
    const float* Wk  = (const float*)d_in[1];
    const float* Wq  = (const float*)d_in[2];
    const float* Wv  = (const float*)d_in[3];
    float* out = (float*)d_out;

    // ws (shorts): Wt[393216] | Q | K | V | Vt (2097152 each) | po u16[1088*16384] | pml f32
    unsigned short* Wt  = (unsigned short*)d_ws;
    unsigned short* Qb  = Wt + 3 * 131072;
    unsigned short* Kb  = Qb + 2097152;
    unsigned short* Vb  = Kb + 2097152;
    unsigned short* Vtb = Vb + 2097152;
    unsigned short* po  = Vtb + 2097152;
    float* pml = (float*)(po + (size_t)1088 * 16384);

    wt_kernel<<<1536, 256, 0, stream>>>(Wq, Wk, Wv, Wt);
    proj_kernel<<<dim3(128, 3), 256, 0, stream>>>(ctx, Wt, Qb);
    vt_kernel<<<256, 256, 0, stream>>>(Vb, Vtb);
    attn_kernel<<<1088, 256, 0, stream>>>(Qb, Kb, Vtb, po, pml);
    combine_kernel<<<2048, 256, 0, stream>>>(po, pml, out);
}

// Round 6
// 176.624 us; speedup vs baseline: 1.4620x; 1.4620x over previous
//
#include <hip/hip_runtime.h>
#include <cstdint>
#include <cstddef>

#define EMBED 1024
#define HEAD  128
#define BATCH 4
#define SEQ   4096
#define KSC   0.04508422f   // log2(e)/sqrt(1024)

typedef __attribute__((ext_vector_type(4))) float f32x4;
typedef __attribute__((ext_vector_type(16))) float f32x16;
typedef __attribute__((ext_vector_type(8))) short s16x8;
typedef __attribute__((ext_vector_type(4))) int i32x4;
typedef __attribute__((ext_vector_type(4))) unsigned short u16x4;

__device__ __forceinline__ unsigned short f2bf(float f) {
    union { float f; unsigned u; } v; v.f = f;
    unsigned r = v.u + 0x7fffu + ((v.u >> 16) & 1u);
    return (unsigned short)(r >> 16);
}

__device__ __forceinline__ int cvtpk(float lo, float hi_) {
    int r;
    asm("v_cvt_pk_bf16_f32 %0, %1, %2" : "=v"(r) : "v"(lo), "v"(hi_));
    return r;
}

// ---- W [1024][128] f32 x3 -> Wt [384][1024] bf16 (rows: 0-127 Q, 128-255 K, 256-383 V)
__global__ __launch_bounds__(256) void wt_kernel(const float* __restrict__ Wq,
                                                 const float* __restrict__ Wk,
                                                 const float* __restrict__ Wv,
                                                 unsigned short* __restrict__ Wt) {
    int idx = blockIdx.x * 256 + threadIdx.x;
    int sel = idx >> 17;
    int r   = idx & 131071;
    const float* W = (sel == 0) ? Wq : (sel == 1) ? Wk : Wv;
    int h = r >> 10, k = r & 1023;
    Wt[(size_t)(sel * 128 + h) * EMBED + k] = f2bf(W[(size_t)k * HEAD + h]);
}

// ---- projection GEMM, m93 structure: grid (128, 3), tile 128x128, BK=64,
// 4 waves (2x2), each wave 64x64 = 4x4 16x16 frags
__global__ __launch_bounds__(256) void proj_kernel(const float* __restrict__ ctx,
                                                   const unsigned short* __restrict__ Wt,
                                                   unsigned short* __restrict__ QKV) {
    __shared__ __align__(16) short As[128 * 72];
    __shared__ __align__(16) short Bs[128 * 72];
    const int tid = threadIdx.x;
    const int lane = tid & 63, w = tid >> 6;
    const int wr = w >> 1, wc = w & 1;
    const int lr = lane & 15, lk = lane >> 4;
    const int m0 = blockIdx.x * 128;
    const unsigned short* Wts = Wt + (size_t)blockIdx.y * 131072;
    unsigned short* outp = QKV + (size_t)blockIdx.y * 2097152;

    f32x4 zero = {0.f, 0.f, 0.f, 0.f};
    f32x4 acc[4][4];
    #pragma unroll
    for (int i = 0; i < 4; ++i)
        #pragma unroll
        for (int jn = 0; jn < 4; ++jn) acc[i][jn] = zero;

    for (int kk = 0; kk < EMBED; kk += 64) {
        __syncthreads();
        #pragma unroll
        for (int t = 0; t < 4; ++t) {
            int c = tid + t * 256;             // 1024 chunks of 8 elems
            int row = c >> 3, cg = c & 7;
            const float* src = ctx + (size_t)(m0 + row) * EMBED + kk + cg * 8;
            f32x4 x0 = *(const f32x4*)src;
            f32x4 x1 = *(const f32x4*)(src + 4);
            s16x8 cv;
            cv[0] = (short)f2bf(x0[0]); cv[1] = (short)f2bf(x0[1]);
            cv[2] = (short)f2bf(x0[2]); cv[3] = (short)f2bf(x0[3]);
            cv[4] = (short)f2bf(x1[0]); cv[5] = (short)f2bf(x1[1]);
            cv[6] = (short)f2bf(x1[2]); cv[7] = (short)f2bf(x1[3]);
            *(s16x8*)&As[row * 72 + cg * 8] = cv;
            *(s16x8*)&Bs[row * 72 + cg * 8] =
                *(const s16x8*)(Wts + (size_t)row * EMBED + kk + cg * 8);
        }
        __syncthreads();
        s16x8 af[4][2], bfr[4][2];
        #pragma unroll
        for (int mi = 0; mi < 4; ++mi)
            #pragma unroll
            for (int k2 = 0; k2 < 2; ++k2)
                af[mi][k2] = *(const s16x8*)&As[(wr * 64 + mi * 16 + lr) * 72 + k2 * 32 + lk * 8];
        #pragma unroll
        for (int ni = 0; ni < 4; ++ni)
            #pragma unroll
            for (int k2 = 0; k2 < 2; ++k2)
                bfr[ni][k2] = *(const s16x8*)&Bs[(wc * 64 + ni * 16 + lr) * 72 + k2 * 32 + lk * 8];
        #pragma unroll
        for (int k2 = 0; k2 < 2; ++k2)
            #pragma unroll
            for (int mi = 0; mi < 4; ++mi)
                #pragma unroll
                for (int ni = 0; ni < 4; ++ni)
                    acc[mi][ni] = __builtin_amdgcn_mfma_f32_16x16x32_bf16(af[mi][k2], bfr[ni][k2], acc[mi][ni], 0, 0, 0);
    }
    #pragma unroll
    for (int mi = 0; mi < 4; ++mi) {
        int row = m0 + wr * 64 + mi * 16 + lk * 4;
        #pragma unroll
        for (int ni = 0; ni < 4; ++ni) {
            int col = wc * 64 + ni * 16 + lr;
            #pragma unroll
            for (int r = 0; r < 4; ++r)
                outp[(size_t)(row + r) * HEAD + col] = f2bf(acc[mi][ni][r]);
        }
    }
}

// ---- V [B*T][128] bf16 -> Vt [B][128][T] bf16
__global__ __launch_bounds__(256) void vt_kernel(const unsigned short* __restrict__ V,
                                                 unsigned short* __restrict__ Vt) {
    __shared__ __align__(16) unsigned short L[64][136];
    const int tid = threadIdx.x;
    const int t0 = blockIdx.x * 64;
    const int b  = t0 >> 12;
    const int tl = t0 & (SEQ - 1);
    #pragma unroll
    for (int j = 0; j < 4; ++j) {
        int c = tid + j * 256;
        int row = c >> 4, cg = c & 15;
        *(s16x8*)&L[row][cg * 8] =
            *(const s16x8*)(V + (size_t)(t0 + row) * HEAD + cg * 8);
    }
    __syncthreads();
    #pragma unroll
    for (int j = 0; j < 4; ++j) {
        int c = tid + j * 256;
        int h = c >> 3, tg = c & 7;
        s16x8 y;
        #pragma unroll
        for (int e = 0; e < 8; ++e) y[e] = (short)L[tg * 8 + e][h];
        *(s16x8*)(Vt + ((size_t)b * HEAD + h) * SEQ + tl + tg * 8) = y;
    }
}

// ---- flash attention: 4 waves x 32 q-rows, 32x32x16 MFMA, swapped QK^T,
// in-register softmax, KV chunks of 256 keys, single-buffered LDS (32KB),
// T14 reg-staged early-issue loads. launch_bounds(256,2): VGPR ~116, no spill;
// occupancy then VGPR-limited at 4 blocks/CU (LDS would allow 5).
__global__ __launch_bounds__(256, 2) void attn_kernel(const unsigned short* __restrict__ Q,
                                                      const unsigned short* __restrict__ K,
                                                      const unsigned short* __restrict__ Vt,
                                                      unsigned short* __restrict__ po,
                                                      float* __restrict__ pml) {
    __shared__ __align__(16) char smem[32768];   // K 16KB + Vt 16KB, XOR-swizzled
    const int tid = threadIdx.x;
    const int lane = tid & 63, w = tid >> 6;
    const int l31 = lane & 31, hi = lane >> 5;
    const int hi16 = hi << 4;

    const int b = blockIdx.x / 272;
    int t = blockIdx.x % 272;
    int qt = 0, cum = 0;
    while (cum + ((qt >> 1) + 1) <= t) { cum += (qt >> 1) + 1; ++qt; }
    const int c = t - cum;
    const int nj = min(4, 2 * qt + 2 - 4 * c);
    const int kb0 = c * 256;
    const int slot = b * 272 + cum + c;

    // Q fragments in registers: Q[q=l31 (+w*32)][d = dt*16 + hi*8 + e]
    const unsigned short* qp = Q + ((size_t)(b * SEQ + qt * 128 + w * 32 + l31)) * HEAD + hi * 8;
    s16x8 qf[8];
    #pragma unroll
    for (int dt = 0; dt < 8; ++dt) qf[dt] = *(const s16x8*)(qp + dt * 16);

    f32x16 o0, o1, o2, o3;
    #pragma unroll
    for (int r = 0; r < 16; ++r) { o0[r] = 0.f; o1[r] = 0.f; o2[r] = 0.f; o3[r] = 0.f; }
    float m_run = -1e30f, l_run = 0.f;

    const int krow = tid >> 4, kch = tid & 15;   // K stage: 16 rows x 16 chunks per pass
    const int vdr  = tid >> 3, vch = tid & 7;    // V stage: 32 rows x 8 chunks per pass

    s16x8 kst[4], vst[4];
    #pragma unroll
    for (int p = 0; p < 4; ++p) {
        kst[p] = *(const s16x8*)(K + ((size_t)(b * SEQ + kb0 + krow + p * 16)) * HEAD + kch * 8);
        vst[p] = *(const s16x8*)(Vt + ((size_t)(b * HEAD + vdr + p * 32)) * SEQ + kb0 + vch * 8);
    }
    #pragma unroll
    for (int p = 0; p < 4; ++p) {
        int r0 = krow + p * 16;
        *(s16x8*)(smem + r0 * 256 + ((kch * 16) ^ ((r0 & 7) << 4))) = kst[p];
        int d0 = vdr + p * 32;
        *(s16x8*)(smem + 16384 + d0 * 128 + ((vch * 16) ^ ((d0 & 7) << 4))) = vst[p];
    }
    __syncthreads();

    for (int j = 0; j < nj; ++j) {
        const int kb = kb0 + j * 64;
        if (j + 1 < nj) {                        // early-issue next-tile loads (T14)
            int kbn = kb + 64;
            #pragma unroll
            for (int p = 0; p < 4; ++p) {
                kst[p] = *(const s16x8*)(K + ((size_t)(b * SEQ + kbn + krow + p * 16)) * HEAD + kch * 8);
                vst[p] = *(const s16x8*)(Vt + ((size_t)(b * HEAD + vdr + p * 32)) * SEQ + kbn + vch * 8);
            }
        }

        // ---- QK^T swapped: st[t][r] = S[k = 32t + crow(r,hi)][q = l31]
        f32x16 st0, st1;
        #pragma unroll
        for (int r = 0; r < 16; ++r) { st0[r] = 0.f; st1[r] = 0.f; }
        const int sw = (l31 & 7) << 4;
        const char* kbase0 = smem + l31 * 256;
        const char* kbase1 = kbase0 + 32 * 256;
        __builtin_amdgcn_s_setprio(1);
        #pragma unroll
        for (int dt = 0; dt < 8; ++dt) {
            s16x8 ka0 = *(const s16x8*)(kbase0 + ((dt * 32 + hi16) ^ sw));
            s16x8 ka1 = *(const s16x8*)(kbase1 + ((dt * 32 + hi16) ^ sw));
            st0 = __builtin_amdgcn_mfma_f32_32x32x16_bf16(ka0, qf[dt], st0, 0, 0, 0);
            st1 = __builtin_amdgcn_mfma_f32_32x32x16_bf16(ka1, qf[dt], st1, 0, 0, 0);
        }
        __builtin_amdgcn_s_setprio(0);

        // ---- causal mask (diagonal tiles only)
        if (4 * c + j >= 2 * qt) {
            const int qg = qt * 128 + w * 32 + l31;
            #pragma unroll
            for (int r = 0; r < 16; ++r) {
                int crow = (r & 3) + 8 * (r >> 2) + 4 * hi;
                if (kb + crow > qg)      st0[r] = -3e37f;
                if (kb + 32 + crow > qg) st1[r] = -3e37f;
            }
        }

        // ---- online softmax, fully in-register (one cross-half shuffle)
        float mx = st0[0];
        #pragma unroll
        for (int r = 1; r < 16; ++r) mx = fmaxf(mx, st0[r]);
        #pragma unroll
        for (int r = 0; r < 16; ++r) mx = fmaxf(mx, st1[r]);
        mx = fmaxf(mx, __shfl_xor(mx, 32));
        float mt = mx * KSC;
        if (!__all(mt <= m_run + 8.0f)) {        // defer-max (T13)
            float mn = fmaxf(m_run, mt);
            float f = exp2f(m_run - mn);
            l_run *= f;
            int fi = __float_as_int(f);
            #pragma unroll
            for (int r = 0; r < 16; ++r) {       // transpose f to reg-domain q
                int srcb = 4 * ((r & 3) + 8 * (r >> 2)) + 16 * hi;
                float fr = __int_as_float(__builtin_amdgcn_ds_bpermute(srcb, fi));
                o0[r] *= fr; o1[r] *= fr; o2[r] *= fr; o3[r] *= fr;
            }
            m_run = mn;
        }
        float rs = 0.f;
        #pragma unroll
        for (int r = 0; r < 16; ++r) {
            st0[r] = exp2f(fmaf(st0[r], KSC, -m_run)); rs += st0[r];
            st1[r] = exp2f(fmaf(st1[r], KSC, -m_run)); rs += st1[r];
        }
        rs += __shfl_xor(rs, 32);
        l_run += rs;

        // ---- P -> bf16 PV A-frags in-register (T12: cvt_pk + permlane32_swap)
        int a0 = cvtpk(st0[0], st0[1]),   b0 = cvtpk(st0[4], st0[5]);
        int a1 = cvtpk(st0[2], st0[3]),   b1 = cvtpk(st0[6], st0[7]);
        int a2 = cvtpk(st0[8], st0[9]),   b2 = cvtpk(st0[12], st0[13]);
        int a3 = cvtpk(st0[10], st0[11]), b3 = cvtpk(st0[14], st0[15]);
        int a4 = cvtpk(st1[0], st1[1]),   b4 = cvtpk(st1[4], st1[5]);
        int a5 = cvtpk(st1[2], st1[3]),   b5 = cvtpk(st1[6], st1[7]);
        int a6 = cvtpk(st1[8], st1[9]),   b6 = cvtpk(st1[12], st1[13]);
        int a7 = cvtpk(st1[10], st1[11]), b7 = cvtpk(st1[14], st1[15]);
        asm volatile("v_permlane32_swap_b32 %0, %1" : "+v"(a0), "+v"(b0));
        asm volatile("v_permlane32_swap_b32 %0, %1" : "+v"(a1), "+v"(b1));
        asm volatile("v_permlane32_swap_b32 %0, %1" : "+v"(a2), "+v"(b2));
        asm volatile("v_permlane32_swap_b32 %0, %1" : "+v"(a3), "+v"(b3));
        asm volatile("v_permlane32_swap_b32 %0, %1" : "+v"(a4), "+v"(b4));
        asm volatile("v_permlane32_swap_b32 %0, %1" : "+v"(a5), "+v"(b5));
        asm volatile("v_permlane32_swap_b32 %0, %1" : "+v"(a6), "+v"(b6));
        asm volatile("v_permlane32_swap_b32 %0, %1" : "+v"(a7), "+v"(b7));
        i32x4 pw0 = {a0, a1, b0, b1}; s16x8 pa0 = *(s16x8*)&pw0;
        i32x4 pw1 = {a2, a3, b2, b3}; s16x8 pa1 = *(s16x8*)&pw1;
        i32x4 pw2 = {a4, a5, b4, b5}; s16x8 pa2 = *(s16x8*)&pw2;
        i32x4 pw3 = {a6, a7, b6, b7}; s16x8 pa3 = *(s16x8*)&pw3;

        // ---- PV: o[nt] += P(32x64) * V(64 x 32d-tile)
        __builtin_amdgcn_s_setprio(1);
        #define PV_NT(oo, nt) { \
            const int vr = (nt) * 32 + l31; \
            const int vsw = (vr & 7) << 4; \
            const char* vb = smem + 16384 + vr * 128; \
            oo = __builtin_amdgcn_mfma_f32_32x32x16_bf16(pa0, *(const s16x8*)(vb + ((0  + hi16) ^ vsw)), oo, 0, 0, 0); \
            oo = __builtin_amdgcn_mfma_f32_32x32x16_bf16(pa1, *(const s16x8*)(vb + ((32 + hi16) ^ vsw)), oo, 0, 0, 0); \
            oo = __builtin_amdgcn_mfma_f32_32x32x16_bf16(pa2, *(const s16x8*)(vb + ((64 + hi16) ^ vsw)), oo, 0, 0, 0); \
            oo = __builtin_amdgcn_mfma_f32_32x32x16_bf16(pa3, *(const s16x8*)(vb + ((96 + hi16) ^ vsw)), oo, 0, 0, 0); }
        PV_NT(o0, 0) PV_NT(o1, 1) PV_NT(o2, 2) PV_NT(o3, 3)
        #undef PV_NT
        __builtin_amdgcn_s_setprio(0);

        if (j + 1 < nj) {                        // single buffer: wait for readers, then overwrite
            __syncthreads();
            #pragma unroll
            for (int p = 0; p < 4; ++p) {
                int r0 = krow + p * 16;
                *(s16x8*)(smem + r0 * 256 + ((kch * 16) ^ ((r0 & 7) << 4))) = kst[p];
                int d0 = vdr + p * 32;
                *(s16x8*)(smem + 16384 + d0 * 128 + ((vch * 16) ^ ((d0 & 7) << 4))) = vst[p];
            }
            __syncthreads();
        }
    }

    // ---- write partials: O is q=crow(reg), d=lane
    unsigned short* pob = po + (size_t)slot * 16384;
    #define STORE_NT(oo, nt) { \
        _Pragma("unroll") \
        for (int r = 0; r < 16; ++r) { \
            int qin = w * 32 + (r & 3) + 8 * (r >> 2) + 4 * hi; \
            pob[qin * 128 + (nt) * 32 + l31] = f2bf(oo[r]); \
        } }
    STORE_NT(o0, 0) STORE_NT(o1, 1) STORE_NT(o2, 2) STORE_NT(o3, 3)
    #undef STORE_NT
    if (lane < 32) {
        float* pm = pml + (size_t)slot * 256 + (w * 32 + lane) * 2;
        pm[0] = m_run; pm[1] = l_run;
    }
}

// ---- combine partials: out[q][:] = sum_c w_c*O_c / sum_c w_c*l_c
__global__ __launch_bounds__(256) void combine_kernel(const unsigned short* __restrict__ po,
                                                      const float* __restrict__ pml,
                                                      float* __restrict__ out) {
    const int tid = threadIdx.x;
    const int row = blockIdx.x * 8 + (tid >> 5);
    const int l32 = tid & 31;
    const int b = row >> 12, q = row & 4095;
    const int qt = q >> 7, qr = q & 127;
    const int nc = (q >> 8) + 1;
    const int cum = ((qt >> 1) + (qt & 1)) * ((qt >> 1) + 1);
    const size_t bslot = (size_t)b * 272 + cum;

    float M = -1e30f;
    for (int cc = 0; cc < nc; ++cc)
        M = fmaxf(M, pml[(bslot + cc) * 256 + qr * 2]);
    float L = 0.f;
    f32x4 acc = {0.f, 0.f, 0.f, 0.f};
    for (int cc = 0; cc < nc; ++cc) {
        const float* pm = pml + (bslot + cc) * 256 + qr * 2;
        float wgt = exp2f(pm[0] - M);
        L += wgt * pm[1];
        u16x4 x = *(const u16x4*)(po + (bslot + cc) * 16384 + qr * 128 + l32 * 4);
        #pragma unroll
        for (int e = 0; e < 4; ++e) {
            union { unsigned u; float f; } cv; cv.u = ((unsigned)x[e]) << 16;
            acc[e] += wgt * cv.f;
        }
    }
    float inv = 1.f / L;
    f32x4 y = {acc[0] * inv, acc[1] * inv, acc[2] * inv, acc[3] * inv};
    *(f32x4*)(out + (size_t)row * HEAD + l32 * 4) = y;
}

extern "C" void kernel_launch(void* const* d_in, const int* in_sizes, int n_in,
                              void* d_out, int out_size, void* d_ws, size_t ws_size,
                              hipStream_t stream) {
    const float* ctx = (const float*)d_in[0];
    const float* Wk  = (const float*)d_in[1];
    const float* Wq  = (const float*)d_in[2];
    const float* Wv  = (const float*)d_in[3];
    float* out = (float*)d_out;

    // ws (shorts): Wt[393216] | Q | K | V | Vt (2097152 each) | po u16[1088*16384] | pml f32
    unsigned short* Wt  = (unsigned short*)d_ws;
    unsigned short* Qb  = Wt + 3 * 131072;
    unsigned short* Kb  = Qb + 2097152;
    unsigned short* Vb  = Kb + 2097152;
    unsigned short* Vtb = Vb + 2097152;
    unsigned short* po  = Vtb + 2097152;
    float* pml = (float*)(po + (size_t)1088 * 16384);

    wt_kernel<<<1536, 256, 0, stream>>>(Wq, Wk, Wv, Wt);
    proj_kernel<<<dim3(128, 3), 256, 0, stream>>>(ctx, Wt, Qb);
    vt_kernel<<<256, 256, 0, stream>>>(Vb, Vtb);
    attn_kernel<<<1088, 256, 0, stream>>>(Qb, Kb, Vtb, po, pml);
    combine_kernel<<<2048, 256, 0, stream>>>(po, pml, out);
}

// Round 8
// 163.499 us; speedup vs baseline: 1.5794x; 1.0803x over previous
//
#include <hip/hip_runtime.h>
#include <cstdint>
#include <cstddef>

#define EMBED 1024
#define HEAD  128
#define BATCH 4
#define SEQ   4096
#define KSC   0.04508422f   // log2(e)/sqrt(1024)

typedef __attribute__((ext_vector_type(4))) float f32x4;
typedef __attribute__((ext_vector_type(16))) float f32x16;
typedef __attribute__((ext_vector_type(8))) short s16x8;
typedef __attribute__((ext_vector_type(4))) int i32x4;
typedef __attribute__((ext_vector_type(4))) unsigned short u16x4;

__device__ __forceinline__ unsigned short f2bf(float f) {
    union { float f; unsigned u; } v; v.f = f;
    unsigned r = v.u + 0x7fffu + ((v.u >> 16) & 1u);
    return (unsigned short)(r >> 16);
}

__device__ __forceinline__ int cvtpk(float lo, float hi_) {
    int r;
    asm("v_cvt_pk_bf16_f32 %0, %1, %2" : "=v"(r) : "v"(lo), "v"(hi_));
    return r;
}

// ---- W [1024][128] f32 x3 -> Wt [384][1024] bf16, coalesced via LDS transpose
// grid 96: sel = blk>>5, k-tile of 32 = blk&31
__global__ __launch_bounds__(256) void wt_kernel(const float* __restrict__ Wq,
                                                 const float* __restrict__ Wk,
                                                 const float* __restrict__ Wv,
                                                 unsigned short* __restrict__ Wt) {
    __shared__ __align__(16) float Lw[32 * 132];
    const int tid = threadIdx.x;
    const int sel = blockIdx.x >> 5;
    const int k0  = (blockIdx.x & 31) * 32;
    const float* W = (sel == 0) ? Wq : (sel == 1) ? Wk : Wv;
    #pragma unroll
    for (int t = 0; t < 4; ++t) {
        int c = tid + t * 256;
        int kk = c >> 5, hc = c & 31;
        *(f32x4*)&Lw[kk * 132 + hc * 4] =
            *(const f32x4*)(W + (size_t)(k0 + kk) * HEAD + hc * 4);
    }
    __syncthreads();
    #pragma unroll
    for (int t = 0; t < 2; ++t) {
        int c = tid + t * 256;
        int h = c >> 2, cg = c & 3;
        int p0 = cvtpk(Lw[(cg * 8 + 0) * 132 + h], Lw[(cg * 8 + 1) * 132 + h]);
        int p1 = cvtpk(Lw[(cg * 8 + 2) * 132 + h], Lw[(cg * 8 + 3) * 132 + h]);
        int p2 = cvtpk(Lw[(cg * 8 + 4) * 132 + h], Lw[(cg * 8 + 5) * 132 + h]);
        int p3 = cvtpk(Lw[(cg * 8 + 6) * 132 + h], Lw[(cg * 8 + 7) * 132 + h]);
        i32x4 pk = {p0, p1, p2, p3};
        *(s16x8*)(Wt + (size_t)(sel * 128 + h) * EMBED + k0 + cg * 8) = *(s16x8*)&pk;
    }
}

// ---- projection GEMM: grid (256, 3), tile 64x128, BK=64, 4 waves (2x2),
// each wave 32x64 = 2x4 16x16 frags. sel0: Q (pre-scaled by KSC), sel1: K,
// sel2: writes V TRANSPOSED directly (Vt [B][128][T]) -- vt_kernel eliminated.
__global__ __launch_bounds__(256) void proj_kernel(const float* __restrict__ ctx,
                                                   const unsigned short* __restrict__ Wt,
                                                   unsigned short* __restrict__ Qb,
                                                   unsigned short* __restrict__ Kb,
                                                   unsigned short* __restrict__ Vtb) {
    __shared__ __align__(16) short As[64 * 72];
    __shared__ __align__(16) short Bs[128 * 72];
    const int tid = threadIdx.x;
    const int lane = tid & 63, w = tid >> 6;
    const int wr = w >> 1, wc = w & 1;
    const int lr = lane & 15, lk = lane >> 4;
    const int m0 = blockIdx.x * 64;
    const int sel = blockIdx.y;
    const unsigned short* Wts = Wt + (size_t)sel * 131072;

    f32x4 zero = {0.f, 0.f, 0.f, 0.f};
    f32x4 acc[2][4];
    #pragma unroll
    for (int i = 0; i < 2; ++i)
        #pragma unroll
        for (int jn = 0; jn < 4; ++jn) acc[i][jn] = zero;

    for (int kk = 0; kk < EMBED; kk += 64) {
        __syncthreads();
        // A: 64 rows x 64 k fp32 -> bf16 via v_cvt_pk (512 chunks of 8, 2/thread)
        #pragma unroll
        for (int t = 0; t < 2; ++t) {
            int c = tid + t * 256;
            int row = c >> 3, cg = c & 7;
            const float* src = ctx + (size_t)(m0 + row) * EMBED + kk + cg * 8;
            f32x4 x0 = *(const f32x4*)src;
            f32x4 x1 = *(const f32x4*)(src + 4);
            int p0 = cvtpk(x0[0], x0[1]);
            int p1 = cvtpk(x0[2], x0[3]);
            int p2 = cvtpk(x1[0], x1[1]);
            int p3 = cvtpk(x1[2], x1[3]);
            i32x4 pk = {p0, p1, p2, p3};
            *(s16x8*)&As[row * 72 + cg * 8] = *(s16x8*)&pk;
        }
        // B: 128 rows x 64 k bf16 (1024 chunks of 8, 4/thread)
        #pragma unroll
        for (int t = 0; t < 4; ++t) {
            int c = tid + t * 256;
            int row = c >> 3, cg = c & 7;
            *(s16x8*)&Bs[row * 72 + cg * 8] =
                *(const s16x8*)(Wts + (size_t)row * EMBED + kk + cg * 8);
        }
        __syncthreads();
        s16x8 af[2][2], bfr[4][2];
        #pragma unroll
        for (int mi = 0; mi < 2; ++mi)
            #pragma unroll
            for (int k2 = 0; k2 < 2; ++k2)
                af[mi][k2] = *(const s16x8*)&As[(wr * 32 + mi * 16 + lr) * 72 + k2 * 32 + lk * 8];
        #pragma unroll
        for (int ni = 0; ni < 4; ++ni)
            #pragma unroll
            for (int k2 = 0; k2 < 2; ++k2)
                bfr[ni][k2] = *(const s16x8*)&Bs[(wc * 64 + ni * 16 + lr) * 72 + k2 * 32 + lk * 8];
        #pragma unroll
        for (int k2 = 0; k2 < 2; ++k2)
            #pragma unroll
            for (int mi = 0; mi < 2; ++mi)
                #pragma unroll
                for (int ni = 0; ni < 4; ++ni)
                    acc[mi][ni] = __builtin_amdgcn_mfma_f32_16x16x32_bf16(af[mi][k2], bfr[ni][k2], acc[mi][ni], 0, 0, 0);
    }

    if (sel == 2) {
        // V transposed: lane's 4 acc rows are consecutive t -> 8B packed store
        #pragma unroll
        for (int mi = 0; mi < 2; ++mi) {
            int t0r = m0 + wr * 32 + mi * 16 + lk * 4;
            int b = t0r >> 12, tl = t0r & (SEQ - 1);
            #pragma unroll
            for (int ni = 0; ni < 4; ++ni) {
                int col = wc * 64 + ni * 16 + lr;
                u16x4 vv;
                #pragma unroll
                for (int r = 0; r < 4; ++r) vv[r] = f2bf(acc[mi][ni][r]);
                *(u16x4*)(Vtb + ((size_t)(b * HEAD + col)) * SEQ + tl) = vv;
            }
        }
    } else {
        unsigned short* outp = sel ? Kb : Qb;
        const float sc = sel ? 1.0f : KSC;   // fold softmax scale into Q
        #pragma unroll
        for (int mi = 0; mi < 2; ++mi) {
            int row = m0 + wr * 32 + mi * 16 + lk * 4;
            #pragma unroll
            for (int ni = 0; ni < 4; ++ni) {
                int col = wc * 64 + ni * 16 + lr;
                #pragma unroll
                for (int r = 0; r < 4; ++r)
                    outp[(size_t)(row + r) * HEAD + col] = f2bf(acc[mi][ni][r] * sc);
            }
        }
    }
}

// ---- flash attention: 4 waves x 32 q-rows, 32x32x16 MFMA, swapped QK^T,
// in-register softmax (Q pre-scaled: S already in log2 domain), KV chunks of
// 256 keys, single-buffered 32KB LDS, T14 reg-staged early-issue loads.
__global__ __launch_bounds__(256, 2) void attn_kernel(const unsigned short* __restrict__ Q,
                                                      const unsigned short* __restrict__ K,
                                                      const unsigned short* __restrict__ Vt,
                                                      unsigned short* __restrict__ po,
                                                      float* __restrict__ pml) {
    __shared__ __align__(16) char smem[32768];   // K 16KB + Vt 16KB, XOR-swizzled
    const int tid = threadIdx.x;
    const int lane = tid & 63, w = tid >> 6;
    const int l31 = lane & 31, hi = lane >> 5;
    const int hi16 = hi << 4;

    const int b = blockIdx.x / 272;
    int t = blockIdx.x % 272;
    int qt = 0, cum = 0;
    while (cum + ((qt >> 1) + 1) <= t) { cum += (qt >> 1) + 1; ++qt; }
    const int c = t - cum;
    const int nj = min(4, 2 * qt + 2 - 4 * c);
    const int kb0 = c * 256;
    const int slot = b * 272 + cum + c;

    const unsigned short* qp = Q + ((size_t)(b * SEQ + qt * 128 + w * 32 + l31)) * HEAD + hi * 8;
    s16x8 qf[8];
    #pragma unroll
    for (int dt = 0; dt < 8; ++dt) qf[dt] = *(const s16x8*)(qp + dt * 16);

    f32x16 o0, o1, o2, o3;
    #pragma unroll
    for (int r = 0; r < 16; ++r) { o0[r] = 0.f; o1[r] = 0.f; o2[r] = 0.f; o3[r] = 0.f; }
    float m_run = -1e30f, l_run = 0.f;

    const int krow = tid >> 4, kch = tid & 15;
    const int vdr  = tid >> 3, vch = tid & 7;

    s16x8 kst[4], vst[4];
    #pragma unroll
    for (int p = 0; p < 4; ++p) {
        kst[p] = *(const s16x8*)(K + ((size_t)(b * SEQ + kb0 + krow + p * 16)) * HEAD + kch * 8);
        vst[p] = *(const s16x8*)(Vt + ((size_t)(b * HEAD + vdr + p * 32)) * SEQ + kb0 + vch * 8);
    }
    #pragma unroll
    for (int p = 0; p < 4; ++p) {
        int r0 = krow + p * 16;
        *(s16x8*)(smem + r0 * 256 + ((kch * 16) ^ ((r0 & 7) << 4))) = kst[p];
        int d0 = vdr + p * 32;
        *(s16x8*)(smem + 16384 + d0 * 128 + ((vch * 16) ^ ((d0 & 7) << 4))) = vst[p];
    }
    __syncthreads();

    for (int j = 0; j < nj; ++j) {
        const int kb = kb0 + j * 64;
        if (j + 1 < nj) {                        // early-issue next-tile loads (T14)
            int kbn = kb + 64;
            #pragma unroll
            for (int p = 0; p < 4; ++p) {
                kst[p] = *(const s16x8*)(K + ((size_t)(b * SEQ + kbn + krow + p * 16)) * HEAD + kch * 8);
                vst[p] = *(const s16x8*)(Vt + ((size_t)(b * HEAD + vdr + p * 32)) * SEQ + kbn + vch * 8);
            }
        }

        // ---- QK^T swapped: st[t][r] = S_log2[k = 32t + crow(r,hi)][q = l31]
        f32x16 st0, st1;
        #pragma unroll
        for (int r = 0; r < 16; ++r) { st0[r] = 0.f; st1[r] = 0.f; }
        const int sw = (l31 & 7) << 4;
        const char* kbase0 = smem + l31 * 256;
        const char* kbase1 = kbase0 + 32 * 256;
        __builtin_amdgcn_s_setprio(1);
        #pragma unroll
        for (int dt = 0; dt < 8; ++dt) {
            s16x8 ka0 = *(const s16x8*)(kbase0 + ((dt * 32 + hi16) ^ sw));
            s16x8 ka1 = *(const s16x8*)(kbase1 + ((dt * 32 + hi16) ^ sw));
            st0 = __builtin_amdgcn_mfma_f32_32x32x16_bf16(ka0, qf[dt], st0, 0, 0, 0);
            st1 = __builtin_amdgcn_mfma_f32_32x32x16_bf16(ka1, qf[dt], st1, 0, 0, 0);
        }
        __builtin_amdgcn_s_setprio(0);

        // ---- causal mask (diagonal tiles only); S already log2-scaled
        if (4 * c + j >= 2 * qt) {
            const int qg = qt * 128 + w * 32 + l31;
            #pragma unroll
            for (int r = 0; r < 16; ++r) {
                int crow = (r & 3) + 8 * (r >> 2) + 4 * hi;
                if (kb + crow > qg)      st0[r] = -3e37f;
                if (kb + 32 + crow > qg) st1[r] = -3e37f;
            }
        }

        // ---- online softmax, fully in-register (one cross-half shuffle)
        float mx = st0[0];
        #pragma unroll
        for (int r = 1; r < 16; ++r) mx = fmaxf(mx, st0[r]);
        #pragma unroll
        for (int r = 0; r < 16; ++r) mx = fmaxf(mx, st1[r]);
        mx = fmaxf(mx, __shfl_xor(mx, 32));
        if (!__all(mx <= m_run + 8.0f)) {        // defer-max (T13)
            float mn = fmaxf(m_run, mx);
            float f = exp2f(m_run - mn);
            l_run *= f;
            int fi = __float_as_int(f);
            #pragma unroll
            for (int r = 0; r < 16; ++r) {       // transpose f to reg-domain q
                int srcb = 4 * ((r & 3) + 8 * (r >> 2)) + 16 * hi;
                float fr = __int_as_float(__builtin_amdgcn_ds_bpermute(srcb, fi));
                o0[r] *= fr; o1[r] *= fr; o2[r] *= fr; o3[r] *= fr;
            }
            m_run = mn;
        }
        float rs = 0.f;
        #pragma unroll
        for (int r = 0; r < 16; ++r) {
            st0[r] = exp2f(st0[r] - m_run); rs += st0[r];
            st1[r] = exp2f(st1[r] - m_run); rs += st1[r];
        }
        rs += __shfl_xor(rs, 32);
        l_run += rs;

        // ---- P -> bf16 PV A-frags in-register (T12: cvt_pk + permlane32_swap)
        int a0 = cvtpk(st0[0], st0[1]),   b0 = cvtpk(st0[4], st0[5]);
        int a1 = cvtpk(st0[2], st0[3]),   b1 = cvtpk(st0[6], st0[7]);
        int a2 = cvtpk(st0[8], st0[9]),   b2 = cvtpk(st0[12], st0[13]);
        int a3 = cvtpk(st0[10], st0[11]), b3 = cvtpk(st0[14], st0[15]);
        int a4 = cvtpk(st1[0], st1[1]),   b4 = cvtpk(st1[4], st1[5]);
        int a5 = cvtpk(st1[2], st1[3]),   b5 = cvtpk(st1[6], st1[7]);
        int a6 = cvtpk(st1[8], st1[9]),   b6 = cvtpk(st1[12], st1[13]);
        int a7 = cvtpk(st1[10], st1[11]), b7 = cvtpk(st1[14], st1[15]);
        asm volatile("v_permlane32_swap_b32 %0, %1" : "+v"(a0), "+v"(b0));
        asm volatile("v_permlane32_swap_b32 %0, %1" : "+v"(a1), "+v"(b1));
        asm volatile("v_permlane32_swap_b32 %0, %1" : "+v"(a2), "+v"(b2));
        asm volatile("v_permlane32_swap_b32 %0, %1" : "+v"(a3), "+v"(b3));
        asm volatile("v_permlane32_swap_b32 %0, %1" : "+v"(a4), "+v"(b4));
        asm volatile("v_permlane32_swap_b32 %0, %1" : "+v"(a5), "+v"(b5));
        asm volatile("v_permlane32_swap_b32 %0, %1" : "+v"(a6), "+v"(b6));
        asm volatile("v_permlane32_swap_b32 %0, %1" : "+v"(a7), "+v"(b7));
        i32x4 pw0 = {a0, a1, b0, b1}; s16x8 pa0 = *(s16x8*)&pw0;
        i32x4 pw1 = {a2, a3, b2, b3}; s16x8 pa1 = *(s16x8*)&pw1;
        i32x4 pw2 = {a4, a5, b4, b5}; s16x8 pa2 = *(s16x8*)&pw2;
        i32x4 pw3 = {a6, a7, b6, b7}; s16x8 pa3 = *(s16x8*)&pw3;

        // ---- PV: o[nt] += P(32x64) * V(64 x 32d-tile)
        __builtin_amdgcn_s_setprio(1);
        #define PV_NT(oo, nt) { \
            const int vr = (nt) * 32 + l31; \
            const int vsw = (vr & 7) << 4; \
            const char* vb = smem + 16384 + vr * 128; \
            oo = __builtin_amdgcn_mfma_f32_32x32x16_bf16(pa0, *(const s16x8*)(vb + ((0  + hi16) ^ vsw)), oo, 0, 0, 0); \
            oo = __builtin_amdgcn_mfma_f32_32x32x16_bf16(pa1, *(const s16x8*)(vb + ((32 + hi16) ^ vsw)), oo, 0, 0, 0); \
            oo = __builtin_amdgcn_mfma_f32_32x32x16_bf16(pa2, *(const s16x8*)(vb + ((64 + hi16) ^ vsw)), oo, 0, 0, 0); \
            oo = __builtin_amdgcn_mfma_f32_32x32x16_bf16(pa3, *(const s16x8*)(vb + ((96 + hi16) ^ vsw)), oo, 0, 0, 0); }
        PV_NT(o0, 0) PV_NT(o1, 1) PV_NT(o2, 2) PV_NT(o3, 3)
        #undef PV_NT
        __builtin_amdgcn_s_setprio(0);

        if (j + 1 < nj) {                        // single buffer: wait readers, overwrite
            __syncthreads();
            #pragma unroll
            for (int p = 0; p < 4; ++p) {
                int r0 = krow + p * 16;
                *(s16x8*)(smem + r0 * 256 + ((kch * 16) ^ ((r0 & 7) << 4))) = kst[p];
                int d0 = vdr + p * 32;
                *(s16x8*)(smem + 16384 + d0 * 128 + ((vch * 16) ^ ((d0 & 7) << 4))) = vst[p];
            }
            __syncthreads();
        }
    }

    unsigned short* pob = po + (size_t)slot * 16384;
    #define STORE_NT(oo, nt) { \
        _Pragma("unroll") \
        for (int r = 0; r < 16; ++r) { \
            int qin = w * 32 + (r & 3) + 8 * (r >> 2) + 4 * hi; \
            pob[qin * 128 + (nt) * 32 + l31] = f2bf(oo[r]); \
        } }
    STORE_NT(o0, 0) STORE_NT(o1, 1) STORE_NT(o2, 2) STORE_NT(o3, 3)
    #undef STORE_NT
    if (lane < 32) {
        float* pm = pml + (size_t)slot * 256 + (w * 32 + lane) * 2;
        pm[0] = m_run; pm[1] = l_run;
    }
}

// ---- combine partials: out[q][:] = sum_c w_c*O_c / sum_c w_c*l_c
__global__ __launch_bounds__(256) void combine_kernel(const unsigned short* __restrict__ po,
                                                      const float* __restrict__ pml,
                                                      float* __restrict__ out) {
    const int tid = threadIdx.x;
    const int row = blockIdx.x * 8 + (tid >> 5);
    const int l32 = tid & 31;
    const int b = row >> 12, q = row & 4095;
    const int qt = q >> 7, qr = q & 127;
    const int nc = (q >> 8) + 1;
    const int cum = ((qt >> 1) + (qt & 1)) * ((qt >> 1) + 1);
    const size_t bslot = (size_t)b * 272 + cum;

    float M = -1e30f;
    for (int cc = 0; cc < nc; ++cc)
        M = fmaxf(M, pml[(bslot + cc) * 256 + qr * 2]);
    float L = 0.f;
    f32x4 acc = {0.f, 0.f, 0.f, 0.f};
    for (int cc = 0; cc < nc; ++cc) {
        const float* pm = pml + (bslot + cc) * 256 + qr * 2;
        float wgt = exp2f(pm[0] - M);
        L += wgt * pm[1];
        u16x4 x = *(const u16x4*)(po + (bslot + cc) * 16384 + qr * 128 + l32 * 4);
        #pragma unroll
        for (int e = 0; e < 4; ++e) {
            union { unsigned u; float f; } cv; cv.u = ((unsigned)x[e]) << 16;
            acc[e] += wgt * cv.f;
        }
    }
    float inv = 1.f / L;
    f32x4 y = {acc[0] * inv, acc[1] * inv, acc[2] * inv, acc[3] * inv};
    *(f32x4*)(out + (size_t)row * HEAD + l32 * 4) = y;
}

extern "C" void kernel_launch(void* const* d_in, const int* in_sizes, int n_in,
                              void* d_out, int out_size, void* d_ws, size_t ws_size,
                              hipStream_t stream) {
    const float* ctx = (const float*)d_in[0];
    const float* Wk  = (const float*)d_in[1];
    const float* Wq  = (const float*)d_in[2];
    const float* Wv  = (const float*)d_in[3];
    float* out = (float*)d_out;

    // ws (shorts): Wt[393216] | Q | K | Vt (2097152 each) | po u16[1088*16384] | pml f32
    unsigned short* Wt  = (unsigned short*)d_ws;
    unsigned short* Qb  = Wt + 3 * 131072;
    unsigned short* Kb  = Qb + 2097152;
    unsigned short* Vtb = Kb + 2097152;
    unsigned short* po  = Vtb + 2097152;
    float* pml = (float*)(po + (size_t)1088 * 16384);

    wt_kernel<<<96, 256, 0, stream>>>(Wq, Wk, Wv, Wt);
    proj_kernel<<<dim3(256, 3), 256, 0, stream>>>(ctx, Wt, Qb, Kb, Vtb);
    attn_kernel<<<1088, 256, 0, stream>>>(Qb, Kb, Vtb, po, pml);
    combine_kernel<<<2048, 256, 0, stream>>>(po, pml, out);
}